// Round 1
// baseline (145.948 us; speedup 1.0000x reference)
//
#include <hip/hip_runtime.h>

typedef unsigned short u16;
typedef __attribute__((ext_vector_type(8))) short short8;
typedef __attribute__((ext_vector_type(4))) float f32x4;
typedef __attribute__((ext_vector_type(2))) float f32x2;
typedef __attribute__((ext_vector_type(2))) unsigned int u32x2;

#define H 256
#define D 128

static __device__ inline u16 f32_to_bf16(float f) {
    unsigned u = __float_as_uint(f);
    unsigned r = u + 0x7FFFu + ((u >> 16) & 1u);   // RNE
    return (u16)(r >> 16);
}

// ---------------- projection + bias + L2-normalize -> bf16 ----------------
// grid: T/32 blocks, 256 threads. Each block: 32 tokens x 128 outputs.
__global__ __launch_bounds__(256) void proj_norm_kernel(
    const float* __restrict__ X, const float* __restrict__ W,
    const float* __restrict__ bias, u16* __restrict__ out)
{
    __shared__ float xs[16][32];    // [hh][token]
    __shared__ float ws[16][128];   // [hh][d]
    const int tid  = threadIdx.x;
    const int tok0 = blockIdx.x * 32;
    const int tg = tid >> 5;        // 0..7  -> tokens tg*4..+3
    const int dg = tid & 31;        // 0..31 -> d = dg*4..+3

    float acc[4][4] = {{0.f}};

    for (int h0 = 0; h0 < H; h0 += 16) {
        // stage x chunk: xs[hh][t]
        {
            int t  = tid >> 3;
            int hb = (tid & 7) * 2;
            f32x2 v = *(const f32x2*)&X[(size_t)(tok0 + t) * H + h0 + hb];
            xs[hb][t]     = v.x;
            xs[hb + 1][t] = v.y;
        }
        // stage W chunk: ws[hh][d]
        {
            int hh = tid >> 4;
            int d0 = (tid & 15) * 8;
            const f32x4* src = (const f32x4*)&W[(size_t)(h0 + hh) * D + d0];
            *(f32x4*)&ws[hh][d0]     = src[0];
            *(f32x4*)&ws[hh][d0 + 4] = src[1];
        }
        __syncthreads();
        #pragma unroll
        for (int hh = 0; hh < 16; ++hh) {
            f32x4 xv = *(const f32x4*)&xs[hh][tg * 4];
            f32x4 wv = *(const f32x4*)&ws[hh][dg * 4];
            #pragma unroll
            for (int i = 0; i < 4; ++i)
                #pragma unroll
                for (int j = 0; j < 4; ++j)
                    acc[i][j] += xv[i] * wv[j];
        }
        __syncthreads();
    }

    f32x4 bv = *(const f32x4*)&bias[dg * 4];
    #pragma unroll
    for (int i = 0; i < 4; ++i)
        #pragma unroll
        for (int j = 0; j < 4; ++j)
            acc[i][j] += bv[j];

    // L2 norm per token: sum-sq across the 32 dg lanes (same tg)
    #pragma unroll
    for (int i = 0; i < 4; ++i) {
        float ss = acc[i][0]*acc[i][0] + acc[i][1]*acc[i][1]
                 + acc[i][2]*acc[i][2] + acc[i][3]*acc[i][3];
        ss += __shfl_xor(ss, 1);
        ss += __shfl_xor(ss, 2);
        ss += __shfl_xor(ss, 4);
        ss += __shfl_xor(ss, 8);
        ss += __shfl_xor(ss, 16);
        float n   = sqrtf(ss);
        float inv = 1.0f / fmaxf(n, 1e-12f);
        unsigned p0 = (unsigned)f32_to_bf16(acc[i][0]*inv) |
                      ((unsigned)f32_to_bf16(acc[i][1]*inv) << 16);
        unsigned p1 = (unsigned)f32_to_bf16(acc[i][2]*inv) |
                      ((unsigned)f32_to_bf16(acc[i][3]*inv) << 16);
        u32x2 pk; pk.x = p0; pk.y = p1;
        *(u32x2*)&out[(size_t)(tok0 + tg*4 + i) * D + dg * 4] = pk;
    }
}

// ---------------- max-sim: logits[qb][db] = sum_s max_t <q[qb,s], d[db,t]> ----
// block: 256 threads (4 waves). Each block: 2 qb x 8 db. grid = 64*16 = 1024.
// wave w owns doc-token rows [w*32, w*32+32).
__global__ __launch_bounds__(256) void maxsim_kernel(
    const u16* __restrict__ qbf, const u16* __restrict__ dbf,
    float* __restrict__ logits)
{
    __shared__ float smax[4][4][16];   // [wave][nf][col]
    const int tid  = threadIdx.x;
    const int wid  = tid >> 6;
    const int lane = tid & 63;
    const int l15  = lane & 15;
    const int lg   = lane >> 4;

    const int qb0 = (blockIdx.x >> 4) * 2;   // 2 query batches
    const int db0 = (blockIdx.x & 15) * 8;   // 8 doc batches

    // Q fragments in registers: bq[nf][kc]; nf = qs*2 + nf2 (qs in 0..1, s = nf2*16 + col)
    short8 bq[4][4];
    #pragma unroll
    for (int nf = 0; nf < 4; ++nf) {
        int qs  = nf >> 1;
        int nf2 = nf & 1;
        const u16* qrow = qbf + (size_t)((qb0 + qs) * 32 + nf2 * 16 + l15) * D;
        #pragma unroll
        for (int kc = 0; kc < 4; ++kc)
            bq[nf][kc] = *(const short8*)(qrow + kc * 32 + lg * 8);
    }

    for (int dbi = 0; dbi < 8; ++dbi) {
        const int db = db0 + dbi;
        // A fragments: D-tile rows owned by this wave
        short8 af[2][4];
        #pragma unroll
        for (int mf = 0; mf < 2; ++mf) {
            const u16* drow = dbf + (size_t)(db * 128 + wid * 32 + mf * 16 + l15) * D;
            #pragma unroll
            for (int kc = 0; kc < 4; ++kc)
                af[mf][kc] = *(const short8*)(drow + kc * 32 + lg * 8);
        }

        f32x4 acc[2][4];
        #pragma unroll
        for (int mf = 0; mf < 2; ++mf)
            #pragma unroll
            for (int nf = 0; nf < 4; ++nf)
                acc[mf][nf] = (f32x4){0.f, 0.f, 0.f, 0.f};

        #pragma unroll
        for (int kc = 0; kc < 4; ++kc)
            #pragma unroll
            for (int mf = 0; mf < 2; ++mf)
                #pragma unroll
                for (int nf = 0; nf < 4; ++nf)
                    acc[mf][nf] = __builtin_amdgcn_mfma_f32_16x16x32_bf16(
                        af[mf][kc], bq[nf][kc], acc[mf][nf], 0, 0, 0);

        // max over this wave's 32 doc tokens, per (nf, col)
        #pragma unroll
        for (int nf = 0; nf < 4; ++nf) {
            f32x4 a0 = acc[0][nf], a1 = acc[1][nf];
            float m = fmaxf(fmaxf(fmaxf(a0[0], a0[1]), fmaxf(a0[2], a0[3])),
                            fmaxf(fmaxf(a1[0], a1[1]), fmaxf(a1[2], a1[3])));
            m = fmaxf(m, __shfl_xor(m, 16));
            m = fmaxf(m, __shfl_xor(m, 32));
            if (lane < 16) smax[wid][nf][l15] = m;
        }
        __syncthreads();

        if (tid < 64) {
            int qs   = tid >> 5;
            int sidx = tid & 31;
            int nf   = qs * 2 + (sidx >> 4);
            int li   = sidx & 15;
            float v = fmaxf(fmaxf(smax[0][nf][li], smax[1][nf][li]),
                            fmaxf(smax[2][nf][li], smax[3][nf][li]));
            v += __shfl_xor(v, 1);
            v += __shfl_xor(v, 2);
            v += __shfl_xor(v, 4);
            v += __shfl_xor(v, 8);
            v += __shfl_xor(v, 16);
            if (sidx == 0) logits[(size_t)(qb0 + qs) * 128 + db] = v;
        }
        __syncthreads();
    }
}

extern "C" void kernel_launch(void* const* d_in, const int* in_sizes, int n_in,
                              void* d_out, int out_size, void* d_ws, size_t ws_size,
                              hipStream_t stream)
{
    const float* query_h = (const float*)d_in[0];  // [128,32,256]
    const float* doc_h   = (const float*)d_in[1];  // [128,128,256]
    const float* W       = (const float*)d_in[2];  // [256,128]
    const float* bias    = (const float*)d_in[3];  // [128]
    float* logits = (float*)d_out;                 // [128,128]

    u16* qbf = (u16*)d_ws;                         // 4096 x 128 bf16
    u16* dbf = qbf + (size_t)4096 * 128;           // 16384 x 128 bf16

    proj_norm_kernel<<<dim3(128), dim3(256), 0, stream>>>(query_h, W, bias, qbf);
    proj_norm_kernel<<<dim3(512), dim3(256), 0, stream>>>(doc_h,   W, bias, dbf);
    maxsim_kernel<<<dim3(1024), dim3(256), 0, stream>>>(qbf, dbf, logits);
}

// Round 3
// 134.060 us; speedup vs baseline: 1.0887x; 1.0887x over previous
//
#include <hip/hip_runtime.h>

typedef unsigned short u16;
typedef __attribute__((ext_vector_type(8))) short short8;
typedef __attribute__((ext_vector_type(16))) float f32x16;
typedef __attribute__((ext_vector_type(4))) float f32x4;
typedef __attribute__((ext_vector_type(2))) float f32x2;
typedef __attribute__((ext_vector_type(2))) unsigned int u32x2;

#define H 256
#define D 128

static __device__ inline u16 f32_to_bf16(float f) {
    unsigned u = __float_as_uint(f);
    unsigned r = u + 0x7FFFu + ((u >> 16) & 1u);   // RNE
    return (u16)(r >> 16);
}

// ---------------- projection + bias + L2-normalize -> bf16 (fused q+d) -------
// grid: 128 (query) + 512 (doc) blocks, 256 threads. Block: 32 tokens x 128 d.
__global__ __launch_bounds__(256) void proj_norm_fused(
    const float* __restrict__ Xq, const float* __restrict__ Xd,
    const float* __restrict__ W,  const float* __restrict__ bias,
    u16* __restrict__ outq, u16* __restrict__ outd)
{
    __shared__ float xs[16][32];    // [hh][token]
    __shared__ float ws[16][128];   // [hh][d]
    const int blk = blockIdx.x;
    const float* X;
    u16* out;
    int tok0;
    if (blk < 128) { X = Xq; out = outq; tok0 = blk * 32; }
    else           { X = Xd; out = outd; tok0 = (blk - 128) * 32; }

    const int tid = threadIdx.x;
    const int tg = tid >> 5;        // 0..7  -> tokens tg*4..+3
    const int dg = tid & 31;        // 0..31 -> d = dg*4..+3

    float acc[4][4] = {{0.f}};

    for (int h0 = 0; h0 < H; h0 += 16) {
        {
            int t  = tid >> 3;
            int hb = (tid & 7) * 2;
            f32x2 v = *(const f32x2*)&X[(size_t)(tok0 + t) * H + h0 + hb];
            xs[hb][t]     = v.x;
            xs[hb + 1][t] = v.y;
        }
        {
            int hh = tid >> 4;
            int d0 = (tid & 15) * 8;
            const f32x4* src = (const f32x4*)&W[(size_t)(h0 + hh) * D + d0];
            *(f32x4*)&ws[hh][d0]     = src[0];
            *(f32x4*)&ws[hh][d0 + 4] = src[1];
        }
        __syncthreads();
        #pragma unroll
        for (int hh = 0; hh < 16; ++hh) {
            f32x4 xv = *(const f32x4*)&xs[hh][tg * 4];
            f32x4 wv = *(const f32x4*)&ws[hh][dg * 4];
            #pragma unroll
            for (int i = 0; i < 4; ++i)
                #pragma unroll
                for (int j = 0; j < 4; ++j)
                    acc[i][j] += xv[i] * wv[j];
        }
        __syncthreads();
    }

    f32x4 bv = *(const f32x4*)&bias[dg * 4];
    #pragma unroll
    for (int i = 0; i < 4; ++i)
        #pragma unroll
        for (int j = 0; j < 4; ++j)
            acc[i][j] += bv[j];

    #pragma unroll
    for (int i = 0; i < 4; ++i) {
        float ss = acc[i][0]*acc[i][0] + acc[i][1]*acc[i][1]
                 + acc[i][2]*acc[i][2] + acc[i][3]*acc[i][3];
        ss += __shfl_xor(ss, 1);
        ss += __shfl_xor(ss, 2);
        ss += __shfl_xor(ss, 4);
        ss += __shfl_xor(ss, 8);
        ss += __shfl_xor(ss, 16);
        float n   = sqrtf(ss);
        float inv = 1.0f / fmaxf(n, 1e-12f);
        unsigned p0 = (unsigned)f32_to_bf16(acc[i][0]*inv) |
                      ((unsigned)f32_to_bf16(acc[i][1]*inv) << 16);
        unsigned p1 = (unsigned)f32_to_bf16(acc[i][2]*inv) |
                      ((unsigned)f32_to_bf16(acc[i][3]*inv) << 16);
        u32x2 pk; pk.x = p0; pk.y = p1;
        *(u32x2*)&out[(size_t)(tok0 + tg*4 + i) * D + dg * 4] = pk;
    }
}

// ---------------- max-sim v2: 32x32x16 MFMA, barrier-free main loop ----------
// block: 256 threads (4 waves). Tile: 2 qb x 8 db. grid = 64*16 = 1024.
// wave w owns doc-token rows [w*32, w*32+32) of every db.
__global__ __launch_bounds__(256) void maxsim_kernel(
    const u16* __restrict__ qbf, const u16* __restrict__ dbf,
    float* __restrict__ logits)
{
    __shared__ float smax[4][8][2][32];   // [wave][dbi][qs][qcol]
    const int tid  = threadIdx.x;
    const int wid  = tid >> 6;
    const int lane = tid & 63;
    const int l31  = lane & 31;
    const int lg2  = lane >> 5;           // 0/1 -> k offset 0/8

    const int qb0 = (blockIdx.x >> 4) * 2;   // 2 query batches
    const int db0 = (blockIdx.x & 15) * 8;   // 8 doc batches

    // B fragments (Q): bq[qs][kc]; col = q-token s = lane&31, k = kc*16 + lg2*8 + i
    short8 bq[2][8];
    #pragma unroll
    for (int qs = 0; qs < 2; ++qs) {
        const u16* qrow = qbf + (size_t)((qb0 + qs) * 32 + l31) * D + lg2 * 8;
        #pragma unroll
        for (int kc = 0; kc < 8; ++kc)
            bq[qs][kc] = *(const short8*)(qrow + kc * 16);
    }

    const u16* dbase = dbf + (size_t)(db0 * 128 + wid * 32 + l31) * D + lg2 * 8;

    for (int dbi = 0; dbi < 8; ++dbi) {
        const u16* drow = dbase + (size_t)dbi * 128 * D;
        // A fragments: row = doc token = lane&31 (within wave's 32 rows)
        short8 af[8];
        #pragma unroll
        for (int kc = 0; kc < 8; ++kc)
            af[kc] = *(const short8*)(drow + kc * 16);

        f32x16 acc0 = {0.f}, acc1 = {0.f};
        #pragma unroll
        for (int kc = 0; kc < 8; ++kc) {
            acc0 = __builtin_amdgcn_mfma_f32_32x32x16_bf16(af[kc], bq[0][kc], acc0, 0, 0, 0);
            acc1 = __builtin_amdgcn_mfma_f32_32x32x16_bf16(af[kc], bq[1][kc], acc1, 0, 0, 0);
        }

        // in-lane max over this lane's 16 doc rows, then partner half via xor(32)
        #pragma unroll
        for (int qs = 0; qs < 2; ++qs) {
            const f32x16 a = qs ? acc1 : acc0;
            float m0 = fmaxf(a[0], a[1]),   m1 = fmaxf(a[2], a[3]);
            float m2 = fmaxf(a[4], a[5]),   m3 = fmaxf(a[6], a[7]);
            float m4 = fmaxf(a[8], a[9]),   m5 = fmaxf(a[10], a[11]);
            float m6 = fmaxf(a[12], a[13]), m7 = fmaxf(a[14], a[15]);
            float m = fmaxf(fmaxf(fmaxf(m0, m1), fmaxf(m2, m3)),
                            fmaxf(fmaxf(m4, m5), fmaxf(m6, m7)));
            m = fmaxf(m, __shfl_xor(m, 32));
            if (lane < 32) smax[wid][dbi][qs][l31] = m;
        }
    }
    __syncthreads();

    // final: for each (dbi, qcol, qs): max over 4 waves, then sum over 32 qcols
    {
        const int dbi = tid >> 5;     // 0..7
        const int col = tid & 31;
        float v0 = fmaxf(fmaxf(smax[0][dbi][0][col], smax[1][dbi][0][col]),
                         fmaxf(smax[2][dbi][0][col], smax[3][dbi][0][col]));
        float v1 = fmaxf(fmaxf(smax[0][dbi][1][col], smax[1][dbi][1][col]),
                         fmaxf(smax[2][dbi][1][col], smax[3][dbi][1][col]));
        v0 += __shfl_xor(v0, 1);  v1 += __shfl_xor(v1, 1);
        v0 += __shfl_xor(v0, 2);  v1 += __shfl_xor(v1, 2);
        v0 += __shfl_xor(v0, 4);  v1 += __shfl_xor(v1, 4);
        v0 += __shfl_xor(v0, 8);  v1 += __shfl_xor(v1, 8);
        v0 += __shfl_xor(v0, 16); v1 += __shfl_xor(v1, 16);
        if (col == 0) {
            logits[(size_t)qb0 * 128 + db0 + dbi]       = v0;
            logits[(size_t)(qb0 + 1) * 128 + db0 + dbi] = v1;
        }
    }
}

extern "C" void kernel_launch(void* const* d_in, const int* in_sizes, int n_in,
                              void* d_out, int out_size, void* d_ws, size_t ws_size,
                              hipStream_t stream)
{
    const float* query_h = (const float*)d_in[0];  // [128,32,256]
    const float* doc_h   = (const float*)d_in[1];  // [128,128,256]
    const float* W       = (const float*)d_in[2];  // [256,128]
    const float* bias    = (const float*)d_in[3];  // [128]
    float* logits = (float*)d_out;                 // [128,128]

    u16* qbf = (u16*)d_ws;                         // 4096 x 128 bf16
    u16* dbf = qbf + (size_t)4096 * 128;           // 16384 x 128 bf16

    proj_norm_fused<<<dim3(640), dim3(256), 0, stream>>>(query_h, doc_h, W, bias, qbf, dbf);
    maxsim_kernel<<<dim3(1024), dim3(256), 0, stream>>>(qbf, dbf, logits);
}

// Round 4
// 131.774 us; speedup vs baseline: 1.1076x; 1.0174x over previous
//
#include <hip/hip_runtime.h>

typedef unsigned short u16;
typedef __attribute__((ext_vector_type(8))) short short8;
typedef __attribute__((ext_vector_type(16))) float f32x16;
typedef __attribute__((ext_vector_type(4))) float f32x4;
typedef __attribute__((ext_vector_type(2))) float f32x2;
typedef __attribute__((ext_vector_type(2))) unsigned int u32x2;

#define H 256
#define D 128

static __device__ inline u16 f32_to_bf16(float f) {
    unsigned u = __float_as_uint(f);
    unsigned r = u + 0x7FFFu + ((u >> 16) & 1u);   // RNE
    return (u16)(r >> 16);
}

// ---------------- projection + bias + L2-normalize -> bf16 (fused q+d) -------
// grid: 128 (query) + 512 (doc) blocks, 256 threads. Block: 32 tokens x 128 d.
// h-chunk = 64: 8 barriers/block (was 32), 1024 FMA between barrier pairs.
__global__ __launch_bounds__(256) void proj_norm_fused(
    const float* __restrict__ Xq, const float* __restrict__ Xd,
    const float* __restrict__ W,  const float* __restrict__ bias,
    u16* __restrict__ outq, u16* __restrict__ outd)
{
    __shared__ float xs[64][33];    // [hh][token], +1 pad: stores 2-way alias (free)
    __shared__ float ws[64][128];   // [hh][d]
    const int blk = blockIdx.x;
    const float* X;
    u16* out;
    int tok0;
    if (blk < 128) { X = Xq; out = outq; tok0 = blk * 32; }
    else           { X = Xd; out = outd; tok0 = (blk - 128) * 32; }

    const int tid = threadIdx.x;
    const int tg = tid >> 5;        // 0..7  -> tokens tg*4..+3
    const int dg = tid & 31;        // 0..31 -> d = dg*4..+3

    float acc[4][4] = {{0.f}};

    for (int h0 = 0; h0 < H; h0 += 64) {
        // stage xs[hh][t]: 32 tokens x 64 h, coalesced f32x4 per lane
        {
            int c  = tid & 15;       // h sub-block
            int tp = tid >> 4;       // 0..15
            #pragma unroll
            for (int pass = 0; pass < 2; ++pass) {
                int t = tp + pass * 16;
                f32x4 v = *(const f32x4*)&X[(size_t)(tok0 + t) * H + h0 + c * 4];
                xs[c*4+0][t] = v.x;
                xs[c*4+1][t] = v.y;
                xs[c*4+2][t] = v.z;
                xs[c*4+3][t] = v.w;
            }
        }
        // stage ws[hh][d]: 64 rows x 128, vector stores
        {
            int dcol = tid & 31;
            int hrow = tid >> 5;     // 0..7
            #pragma unroll
            for (int pass = 0; pass < 8; ++pass) {
                int hh = hrow + pass * 8;
                *(f32x4*)&ws[hh][dcol*4] =
                    *(const f32x4*)&W[(size_t)(h0 + hh) * D + dcol * 4];
            }
        }
        __syncthreads();
        #pragma unroll 8
        for (int hh = 0; hh < 64; ++hh) {
            float x0 = xs[hh][tg*4+0];   // broadcast reads (2 addrs/wave)
            float x1 = xs[hh][tg*4+1];
            float x2 = xs[hh][tg*4+2];
            float x3 = xs[hh][tg*4+3];
            f32x4 wv = *(const f32x4*)&ws[hh][dg*4];
            #pragma unroll
            for (int j = 0; j < 4; ++j) {
                acc[0][j] += x0 * wv[j];
                acc[1][j] += x1 * wv[j];
                acc[2][j] += x2 * wv[j];
                acc[3][j] += x3 * wv[j];
            }
        }
        __syncthreads();
    }

    f32x4 bv = *(const f32x4*)&bias[dg * 4];
    #pragma unroll
    for (int i = 0; i < 4; ++i)
        #pragma unroll
        for (int j = 0; j < 4; ++j)
            acc[i][j] += bv[j];

    #pragma unroll
    for (int i = 0; i < 4; ++i) {
        float ss = acc[i][0]*acc[i][0] + acc[i][1]*acc[i][1]
                 + acc[i][2]*acc[i][2] + acc[i][3]*acc[i][3];
        ss += __shfl_xor(ss, 1);
        ss += __shfl_xor(ss, 2);
        ss += __shfl_xor(ss, 4);
        ss += __shfl_xor(ss, 8);
        ss += __shfl_xor(ss, 16);
        float n   = sqrtf(ss);
        float inv = 1.0f / fmaxf(n, 1e-12f);
        unsigned p0 = (unsigned)f32_to_bf16(acc[i][0]*inv) |
                      ((unsigned)f32_to_bf16(acc[i][1]*inv) << 16);
        unsigned p1 = (unsigned)f32_to_bf16(acc[i][2]*inv) |
                      ((unsigned)f32_to_bf16(acc[i][3]*inv) << 16);
        u32x2 pk; pk.x = p0; pk.y = p1;
        *(u32x2*)&out[(size_t)(tok0 + tg*4 + i) * D + dg * 4] = pk;
    }
}

// ---------------- max-sim v3: 32x32x16 MFMA, reg-double-buffered db loop -----
// block: 256 threads (4 waves). Tile: 2 qb x 8 db. grid = 64*16 = 1024.
// wave w owns doc-token rows [w*32, w*32+32) of every db.
// Loads for db i+1 issue BEFORE the MFMA cluster of db i (L2 latency hidden).

#define LOAD_AF(AF, DBI)                                                       \
    {                                                                          \
        const u16* dr_ = dbase + (size_t)(DBI) * 128 * D;                      \
        _Pragma("unroll")                                                      \
        for (int kc = 0; kc < 8; ++kc)                                         \
            AF[kc] = *(const short8*)(dr_ + kc * 16);                          \
    }

#define COMPUTE_AF(AF, DBI)                                                    \
    {                                                                          \
        f32x16 acc0 = {0.f}, acc1 = {0.f};                                     \
        _Pragma("unroll")                                                      \
        for (int kc = 0; kc < 8; ++kc) {                                       \
            acc0 = __builtin_amdgcn_mfma_f32_32x32x16_bf16(AF[kc], bq[0][kc],  \
                                                           acc0, 0, 0, 0);     \
            acc1 = __builtin_amdgcn_mfma_f32_32x32x16_bf16(AF[kc], bq[1][kc],  \
                                                           acc1, 0, 0, 0);     \
        }                                                                      \
        _Pragma("unroll")                                                      \
        for (int qs = 0; qs < 2; ++qs) {                                       \
            const f32x16 a = qs ? acc1 : acc0;                                 \
            float m0 = fmaxf(a[0], a[1]),   m1 = fmaxf(a[2], a[3]);            \
            float m2 = fmaxf(a[4], a[5]),   m3 = fmaxf(a[6], a[7]);            \
            float m4 = fmaxf(a[8], a[9]),   m5 = fmaxf(a[10], a[11]);          \
            float m6 = fmaxf(a[12], a[13]), m7 = fmaxf(a[14], a[15]);          \
            float m = fmaxf(fmaxf(fmaxf(m0, m1), fmaxf(m2, m3)),               \
                            fmaxf(fmaxf(m4, m5), fmaxf(m6, m7)));              \
            m = fmaxf(m, __shfl_xor(m, 32));                                   \
            if (lane < 32) smax[wid][DBI][qs][l31] = m;                        \
        }                                                                      \
    }

__global__ __launch_bounds__(256) void maxsim_kernel(
    const u16* __restrict__ qbf, const u16* __restrict__ dbf,
    float* __restrict__ logits)
{
    __shared__ float smax[4][8][2][32];   // [wave][dbi][qs][qcol]
    const int tid  = threadIdx.x;
    const int wid  = tid >> 6;
    const int lane = tid & 63;
    const int l31  = lane & 31;
    const int lg2  = lane >> 5;           // 0/1 -> k offset 0/8

    const int qb0 = (blockIdx.x >> 4) * 2;   // 2 query batches
    const int db0 = (blockIdx.x & 15) * 8;   // 8 doc batches

    // B fragments (Q): col = q-token s = lane&31, k = kc*16 + lg2*8 + i
    short8 bq[2][8];
    #pragma unroll
    for (int qs = 0; qs < 2; ++qs) {
        const u16* qrow = qbf + (size_t)((qb0 + qs) * 32 + l31) * D + lg2 * 8;
        #pragma unroll
        for (int kc = 0; kc < 8; ++kc)
            bq[qs][kc] = *(const short8*)(qrow + kc * 16);
    }

    const u16* dbase = dbf + (size_t)(db0 * 128 + wid * 32 + l31) * D + lg2 * 8;

    short8 afA[8], afB[8];
    LOAD_AF(afA, 0);
    #pragma unroll
    for (int dbi = 0; dbi < 8; dbi += 2) {
        LOAD_AF(afB, dbi + 1);
        COMPUTE_AF(afA, dbi);
        if (dbi + 2 < 8) LOAD_AF(afA, dbi + 2);
        COMPUTE_AF(afB, dbi + 1);
    }
    __syncthreads();

    // final: for each (dbi, qcol, qs): max over 4 waves, then sum over 32 qcols
    {
        const int dbi = tid >> 5;     // 0..7
        const int col = tid & 31;
        float v0 = fmaxf(fmaxf(smax[0][dbi][0][col], smax[1][dbi][0][col]),
                         fmaxf(smax[2][dbi][0][col], smax[3][dbi][0][col]));
        float v1 = fmaxf(fmaxf(smax[0][dbi][1][col], smax[1][dbi][1][col]),
                         fmaxf(smax[2][dbi][1][col], smax[3][dbi][1][col]));
        v0 += __shfl_xor(v0, 1);  v1 += __shfl_xor(v1, 1);
        v0 += __shfl_xor(v0, 2);  v1 += __shfl_xor(v1, 2);
        v0 += __shfl_xor(v0, 4);  v1 += __shfl_xor(v1, 4);
        v0 += __shfl_xor(v0, 8);  v1 += __shfl_xor(v1, 8);
        v0 += __shfl_xor(v0, 16); v1 += __shfl_xor(v1, 16);
        if (col == 0) {
            logits[(size_t)qb0 * 128 + db0 + dbi]       = v0;
            logits[(size_t)(qb0 + 1) * 128 + db0 + dbi] = v1;
        }
    }
}

extern "C" void kernel_launch(void* const* d_in, const int* in_sizes, int n_in,
                              void* d_out, int out_size, void* d_ws, size_t ws_size,
                              hipStream_t stream)
{
    const float* query_h = (const float*)d_in[0];  // [128,32,256]
    const float* doc_h   = (const float*)d_in[1];  // [128,128,256]
    const float* W       = (const float*)d_in[2];  // [256,128]
    const float* bias    = (const float*)d_in[3];  // [128]
    float* logits = (float*)d_out;                 // [128,128]

    u16* qbf = (u16*)d_ws;                         // 4096 x 128 bf16
    u16* dbf = qbf + (size_t)4096 * 128;           // 16384 x 128 bf16

    proj_norm_fused<<<dim3(640), dim3(256), 0, stream>>>(query_h, doc_h, W, bias, qbf, dbf);
    maxsim_kernel<<<dim3(1024), dim3(256), 0, stream>>>(qbf, dbf, logits);
}

// Round 5
// 114.548 us; speedup vs baseline: 1.2741x; 1.1504x over previous
//
#include <hip/hip_runtime.h>

typedef unsigned short u16;
typedef __attribute__((ext_vector_type(8))) short short8;
typedef __attribute__((ext_vector_type(16))) float f32x16;
typedef __attribute__((ext_vector_type(4))) float f32x4;
typedef __attribute__((ext_vector_type(2))) float f32x2;
typedef __attribute__((ext_vector_type(4))) unsigned int u32x4;

#define H 256
#define D 128

// Fragment-chunk layout for normalized bf16 embeddings (consumed by maxsim):
//   elem index = tile*4096 + kc*512 + (l31*2 + lg2)*8 + j
//   holds Y[token = tile*32 + l31][k = kc*16 + lg2*8 + j]
// so a wave's 64 lanes (slot = l31*2+lg2) load 1024 CONTIGUOUS bytes per kc
// (fully coalesced; the old row-major layout was 64 cache lines per load).

static __device__ inline u16 f32_to_bf16(float f) {
    unsigned u = __float_as_uint(f);
    unsigned r = u + 0x7FFFu + ((u >> 16) & 1u);   // RNE
    return (u16)(r >> 16);
}

// ---------------- projection + bias + L2-normalize -> bf16 (fused q+d) -------
// grid: 128 (query) + 512 (doc) blocks, 256 threads. Block: 32 tokens x 128 d.
__global__ __launch_bounds__(256) void proj_norm_fused(
    const float* __restrict__ Xq, const float* __restrict__ Xd,
    const float* __restrict__ W,  const float* __restrict__ bias,
    u16* __restrict__ outq, u16* __restrict__ outd)
{
    __shared__ float xs[64][33];    // [hh][token], +1 pad
    __shared__ float ws[64][128];   // [hh][d]
    const int blk = blockIdx.x;
    const float* X;
    u16* out;
    int tok0;
    if (blk < 128) { X = Xq; out = outq; tok0 = blk * 32; }
    else           { X = Xd; out = outd; tok0 = (blk - 128) * 32; }

    const int tid = threadIdx.x;
    const int tg = tid >> 5;        // 0..7  -> tokens tg*4..+3
    const int dg = tid & 31;        // 0..31 -> d = dg*4..+3

    float acc[4][4] = {{0.f}};

    for (int h0 = 0; h0 < H; h0 += 64) {
        {
            int c  = tid & 15;
            int tp = tid >> 4;
            #pragma unroll
            for (int pass = 0; pass < 2; ++pass) {
                int t = tp + pass * 16;
                f32x4 v = *(const f32x4*)&X[(size_t)(tok0 + t) * H + h0 + c * 4];
                xs[c*4+0][t] = v.x;
                xs[c*4+1][t] = v.y;
                xs[c*4+2][t] = v.z;
                xs[c*4+3][t] = v.w;
            }
        }
        {
            int dcol = tid & 31;
            int hrow = tid >> 5;
            #pragma unroll
            for (int pass = 0; pass < 8; ++pass) {
                int hh = hrow + pass * 8;
                *(f32x4*)&ws[hh][dcol*4] =
                    *(const f32x4*)&W[(size_t)(h0 + hh) * D + dcol * 4];
            }
        }
        __syncthreads();
        #pragma unroll 8
        for (int hh = 0; hh < 64; ++hh) {
            float x0 = xs[hh][tg*4+0];
            float x1 = xs[hh][tg*4+1];
            float x2 = xs[hh][tg*4+2];
            float x3 = xs[hh][tg*4+3];
            f32x4 wv = *(const f32x4*)&ws[hh][dg*4];
            #pragma unroll
            for (int j = 0; j < 4; ++j) {
                acc[0][j] += x0 * wv[j];
                acc[1][j] += x1 * wv[j];
                acc[2][j] += x2 * wv[j];
                acc[3][j] += x3 * wv[j];
            }
        }
        __syncthreads();
    }

    f32x4 bv = *(const f32x4*)&bias[dg * 4];
    #pragma unroll
    for (int i = 0; i < 4; ++i)
        #pragma unroll
        for (int j = 0; j < 4; ++j)
            acc[i][j] += bv[j];

    // Epilogue: normalize, pack bf16, write fragment-chunk layout.
    // Thread (tg,dg) owns tokens tg*4+i, d [dg*4, dg*4+4). Chunk c = dg>>1
    // (d [c*8, c*8+8)) is assembled from lane pair (dg even|odd) via shfl.
    const int kc   = dg >> 2;          // c>>1
    const int lg2  = (dg >> 1) & 1;    // c&1
    const int par  = dg & 1;           // 0: own = low half of chunk
    const size_t tileBase = (size_t)(tok0 >> 5) * 4096;

    #pragma unroll
    for (int i = 0; i < 4; ++i) {
        float ss = acc[i][0]*acc[i][0] + acc[i][1]*acc[i][1]
                 + acc[i][2]*acc[i][2] + acc[i][3]*acc[i][3];
        ss += __shfl_xor(ss, 1);
        ss += __shfl_xor(ss, 2);
        ss += __shfl_xor(ss, 4);
        ss += __shfl_xor(ss, 8);
        ss += __shfl_xor(ss, 16);
        float n   = sqrtf(ss);
        float inv = 1.0f / fmaxf(n, 1e-12f);
        unsigned p0 = (unsigned)f32_to_bf16(acc[i][0]*inv) |
                      ((unsigned)f32_to_bf16(acc[i][1]*inv) << 16);
        unsigned p1 = (unsigned)f32_to_bf16(acc[i][2]*inv) |
                      ((unsigned)f32_to_bf16(acc[i][3]*inv) << 16);
        unsigned q0 = __shfl_xor(p0, 1);
        unsigned q1 = __shfl_xor(p1, 1);
        // even lane stores tokens i=0,1; odd lane stores i=2,3 (each a full 16B chunk)
        if ((par == 0) == (i < 2)) {
            u32x4 ck;
            if (par == 0) { ck.x = p0; ck.y = p1; ck.z = q0; ck.w = q1; }
            else          { ck.x = q0; ck.y = q1; ck.z = p0; ck.w = p1; }
            int l31 = tg * 4 + i;
            *(u32x4*)&out[tileBase + kc * 512 + l31 * 16 + lg2 * 8] = ck;
        }
    }
}

// ---------------- max-sim v4: 32x32x16 MFMA, coalesced fragment loads --------
// block: 256 threads (4 waves). Tile: 2 qb x 8 db. grid = 64*16 = 1024.
// wave w owns doc-token rows [w*32, w*32+32) (tile = db*4 + w) of every db.
__global__ __launch_bounds__(256) void maxsim_kernel(
    const u16* __restrict__ qbf, const u16* __restrict__ dbf,
    float* __restrict__ logits)
{
    __shared__ float smax[4][8][2][32];   // [wave][dbi][qs][qcol]
    const int tid  = threadIdx.x;
    const int wid  = tid >> 6;
    const int lane = tid & 63;
    const int l31  = lane & 31;
    const int soff = ((lane & 31) * 2 + (lane >> 5)) * 8;  // this lane's slot, elems

    const int qb0 = (blockIdx.x >> 4) * 2;   // 2 query batches
    const int db0 = (blockIdx.x & 15) * 8;   // 8 doc batches

    // B fragments (Q): bq[qs][kc][j] = Q[qb0+qs][l31][kc*16+lg2*8+j]
    short8 bq[2][8];
    #pragma unroll
    for (int qs = 0; qs < 2; ++qs) {
        const u16* qb_base = qbf + (size_t)(qb0 + qs) * 4096 + soff;
        #pragma unroll
        for (int kc = 0; kc < 8; ++kc)
            bq[qs][kc] = *(const short8*)(qb_base + kc * 512);
    }

    #pragma unroll 2
    for (int dbi = 0; dbi < 8; ++dbi) {
        const u16* dt = dbf + (size_t)((db0 + dbi) * 4 + wid) * 4096 + soff;
        short8 af[8];
        #pragma unroll
        for (int kc = 0; kc < 8; ++kc)
            af[kc] = *(const short8*)(dt + kc * 512);

        f32x16 acc0 = {0.f}, acc1 = {0.f};
        #pragma unroll
        for (int kc = 0; kc < 8; ++kc) {
            acc0 = __builtin_amdgcn_mfma_f32_32x32x16_bf16(af[kc], bq[0][kc], acc0, 0, 0, 0);
            acc1 = __builtin_amdgcn_mfma_f32_32x32x16_bf16(af[kc], bq[1][kc], acc1, 0, 0, 0);
        }

        #pragma unroll
        for (int qs = 0; qs < 2; ++qs) {
            const f32x16 a = qs ? acc1 : acc0;
            float m0 = fmaxf(a[0], a[1]),   m1 = fmaxf(a[2], a[3]);
            float m2 = fmaxf(a[4], a[5]),   m3 = fmaxf(a[6], a[7]);
            float m4 = fmaxf(a[8], a[9]),   m5 = fmaxf(a[10], a[11]);
            float m6 = fmaxf(a[12], a[13]), m7 = fmaxf(a[14], a[15]);
            float m = fmaxf(fmaxf(fmaxf(m0, m1), fmaxf(m2, m3)),
                            fmaxf(fmaxf(m4, m5), fmaxf(m6, m7)));
            m = fmaxf(m, __shfl_xor(m, 32));
            if (lane < 32) smax[wid][dbi][qs][l31] = m;
        }
    }
    __syncthreads();

    // final: per (dbi, qcol, qs): max over 4 waves, then sum over 32 qcols
    {
        const int dbi = tid >> 5;     // 0..7
        const int col = tid & 31;
        float v0 = fmaxf(fmaxf(smax[0][dbi][0][col], smax[1][dbi][0][col]),
                         fmaxf(smax[2][dbi][0][col], smax[3][dbi][0][col]));
        float v1 = fmaxf(fmaxf(smax[0][dbi][1][col], smax[1][dbi][1][col]),
                         fmaxf(smax[2][dbi][1][col], smax[3][dbi][1][col]));
        v0 += __shfl_xor(v0, 1);  v1 += __shfl_xor(v1, 1);
        v0 += __shfl_xor(v0, 2);  v1 += __shfl_xor(v1, 2);
        v0 += __shfl_xor(v0, 4);  v1 += __shfl_xor(v1, 4);
        v0 += __shfl_xor(v0, 8);  v1 += __shfl_xor(v1, 8);
        v0 += __shfl_xor(v0, 16); v1 += __shfl_xor(v1, 16);
        if (col == 0) {
            logits[(size_t)qb0 * 128 + db0 + dbi]       = v0;
            logits[(size_t)(qb0 + 1) * 128 + db0 + dbi] = v1;
        }
    }
}

extern "C" void kernel_launch(void* const* d_in, const int* in_sizes, int n_in,
                              void* d_out, int out_size, void* d_ws, size_t ws_size,
                              hipStream_t stream)
{
    const float* query_h = (const float*)d_in[0];  // [128,32,256]
    const float* doc_h   = (const float*)d_in[1];  // [128,128,256]
    const float* W       = (const float*)d_in[2];  // [256,128]
    const float* bias    = (const float*)d_in[3];  // [128]
    float* logits = (float*)d_out;                 // [128,128]

    u16* qbf = (u16*)d_ws;                         // 128 tiles x 4096 elems (1 MB)
    u16* dbf = qbf + (size_t)128 * 4096;           // 512 tiles x 4096 elems (4 MB)

    proj_norm_fused<<<dim3(640), dim3(256), 0, stream>>>(query_h, doc_h, W, bias, qbf, dbf);
    maxsim_kernel<<<dim3(1024), dim3(256), 0, stream>>>(qbf, dbf, logits);
}

// Round 6
// 105.523 us; speedup vs baseline: 1.3831x; 1.0855x over previous
//
#include <hip/hip_runtime.h>

typedef unsigned short u16;
typedef unsigned int u32;
typedef __attribute__((ext_vector_type(8))) short short8;
typedef __attribute__((ext_vector_type(16))) float f32x16;
typedef __attribute__((ext_vector_type(4))) float f32x4;
typedef __attribute__((ext_vector_type(4))) unsigned int u32x4;

#define H 256
#define D 128

// Fragment-chunk layout for normalized bf16 embeddings (consumed by maxsim):
//   elem index = tile*4096 + kc*512 + (l31*2 + lg2)*8 + j
//   holds Y[token = tile*32 + l31][k = kc*16 + lg2*8 + j]
// A wave's 64 lanes (slot = l31*2+lg2) load/store 1024 CONTIGUOUS bytes per kc.

union V16 { u32x4 u; short8 s; f32x4 f; };

static __device__ inline u32 bf16pk_rne(float a, float b) {
    u32 ua = __float_as_uint(a), ub = __float_as_uint(b);
    ua = ua + 0x7FFFu + ((ua >> 16) & 1u);
    ub = ub + 0x7FFFu + ((ub >> 16) & 1u);
    return (ua >> 16) | (ub & 0xFFFF0000u);
}

// ---------------- prep_w: W (fp32 [H][D]) -> bf16 hi/lo A-fragments ----------
// A-frag (M = embedding dim n): chunk id g = (nt*16 + kc)*64 + slot,
// slot = l31*2 + lg2; elem j holds W[kc*16 + lg2*8 + j][nt*32 + l31].
__global__ __launch_bounds__(256) void prep_w(
    const float* __restrict__ W, u16* __restrict__ whi, u16* __restrict__ wlo)
{
    const int g   = blockIdx.x * 256 + threadIdx.x;   // 0..4095
    const int slot = g & 63;
    const int kc  = (g >> 6) & 15;
    const int nt  = g >> 10;
    const int l31 = slot >> 1;
    const int lg2 = slot & 1;
    const int k0  = kc * 16 + lg2 * 8;
    const int n   = nt * 32 + l31;

    u32 hw[4], lw[4];
    #pragma unroll
    for (int p = 0; p < 4; ++p) {
        float a = W[(size_t)(k0 + 2*p)     * D + n];
        float b = W[(size_t)(k0 + 2*p + 1) * D + n];
        u32 ua = __float_as_uint(a), ub = __float_as_uint(b);
        u32 ha = ua & 0xFFFF0000u,   hb = ub & 0xFFFF0000u;
        hw[p] = (ua >> 16) | hb;                       // hi = truncation (exact lo below)
        float la = a - __uint_as_float(ha);
        float lb = b - __uint_as_float(hb);
        u32 ra = __float_as_uint(la); ra += 0x7FFFu + ((ra >> 16) & 1u);
        u32 rb = __float_as_uint(lb); rb += 0x7FFFu + ((rb >> 16) & 1u);
        lw[p] = (ra >> 16) | (rb & 0xFFFF0000u);       // lo = RNE bf16
    }
    u32x4 hv = {hw[0], hw[1], hw[2], hw[3]};
    u32x4 lv = {lw[0], lw[1], lw[2], lw[3]};
    *(u32x4*)&whi[(size_t)g * 8] = hv;
    *(u32x4*)&wlo[(size_t)g * 8] = lv;
}

// ---------------- proj v2: 3-term bf16-split MFMA + norm -> frag layout ------
// grid: 32 (query) + 128 (doc) blocks x 256 thr. Wave handles 32 tokens.
// D_mfma[n][t] = sum_k Wt[n][k] * X[t][k]:  A = W-frags (ws), B = X (on-the-fly
// hi/lo split). C/D: col = lane&31 = token, row = n = nt*32+(r&3)+8*(r>>2)+4*hi
// -> each token's 128 outputs live in lane pair (l, l+32): in-lane norm + 1 shfl.
__global__ __launch_bounds__(256) void proj_mfma(
    const float* __restrict__ Xq, const float* __restrict__ Xd,
    const float* __restrict__ bias,
    const u16* __restrict__ whi, const u16* __restrict__ wlo,
    u16* __restrict__ outq, u16* __restrict__ outd)
{
    const int tid  = threadIdx.x;
    const int wid  = tid >> 6;
    const int lane = tid & 63;
    const int l31  = lane & 31;
    const int hi   = lane >> 5;
    const int slot = l31 * 2 + hi;

    const float* X; u16* out; int trow0;
    if (blockIdx.x < 32) { X = Xq; out = outq; trow0 = blockIdx.x * 128 + wid * 32; }
    else { X = Xd; out = outd; trow0 = (blockIdx.x - 32) * 128 + wid * 32; }

    const float* xrow = X + (size_t)(trow0 + l31) * H + hi * 8;

    f32x16 acc[4];
    #pragma unroll
    for (int nt = 0; nt < 4; ++nt) acc[nt] = (f32x16){0.f};

    #pragma unroll
    for (int kc = 0; kc < 16; ++kc) {
        V16 a4, b4;
        a4.f = *(const f32x4*)(xrow + kc * 16);
        b4.f = *(const f32x4*)(xrow + kc * 16 + 4);
        float e[8];
        #pragma unroll
        for (int i = 0; i < 4; ++i) { e[i] = a4.f[i]; e[i + 4] = b4.f[i]; }

        V16 xh, xl;
        u32 xhu[4], xlu[4];
        #pragma unroll
        for (int p = 0; p < 4; ++p) {
            u32 u0 = __float_as_uint(e[2*p]), u1 = __float_as_uint(e[2*p+1]);
            u32 h0 = u0 & 0xFFFF0000u,        h1 = u1 & 0xFFFF0000u;
            xhu[p] = (u0 >> 16) | h1;                          // hi = trunc
            float l0 = e[2*p]   - __uint_as_float(h0);         // exact residual
            float l1 = e[2*p+1] - __uint_as_float(h1);
            xlu[p] = (__float_as_uint(l0) >> 16) |
                     (__float_as_uint(l1) & 0xFFFF0000u);      // lo = trunc (2^-15 rel)
        }
        xh.u = (u32x4){xhu[0], xhu[1], xhu[2], xhu[3]};
        xl.u = (u32x4){xlu[0], xlu[1], xlu[2], xlu[3]};

        #pragma unroll
        for (int nt = 0; nt < 4; ++nt) {
            V16 wh, wl;
            const size_t fo = (size_t)((nt * 16 + kc) * 64 + slot) * 8;
            wh.u = *(const u32x4*)&whi[fo];
            wl.u = *(const u32x4*)&wlo[fo];
            acc[nt] = __builtin_amdgcn_mfma_f32_32x32x16_bf16(wh.s, xh.s, acc[nt], 0, 0, 0);
            acc[nt] = __builtin_amdgcn_mfma_f32_32x32x16_bf16(wl.s, xh.s, acc[nt], 0, 0, 0);
            acc[nt] = __builtin_amdgcn_mfma_f32_32x32x16_bf16(wh.s, xl.s, acc[nt], 0, 0, 0);
        }
    }

    // bias + sum-sq (this lane holds 64 of token's 128 outputs; partner has rest)
    float ss = 0.f;
    #pragma unroll
    for (int nt = 0; nt < 4; ++nt) {
        #pragma unroll
        for (int q = 0; q < 4; ++q) {
            f32x4 b4 = *(const f32x4*)&bias[nt * 32 + q * 8 + hi * 4];
            #pragma unroll
            for (int i = 0; i < 4; ++i) {
                float v = acc[nt][q*4+i] + b4[i];
                acc[nt][q*4+i] = v;
                ss += v * v;
            }
        }
    }
    ss += __shfl_xor(ss, 32);
    const float inv = 1.0f / fmaxf(sqrtf(ss), 1e-12f);

    // pack bf16, pair-exchange (l <-> l+32), coalesced frag-layout stores
    const size_t base = (size_t)(trow0 >> 5) * 4096;
    #pragma unroll
    for (int nt = 0; nt < 4; ++nt) {
        #pragma unroll
        for (int q = 0; q < 4; ++q) {
            float v0 = acc[nt][q*4+0] * inv, v1 = acc[nt][q*4+1] * inv;
            float v2 = acc[nt][q*4+2] * inv, v3 = acc[nt][q*4+3] * inv;
            u32 p0 = bf16pk_rne(v0, v1), p1 = bf16pk_rne(v2, v3);
            u32 r0 = __shfl_xor(p0, 32), r1 = __shfl_xor(p1, 32);
            if ((q & 1) == hi) {           // lg2 = q&1 == hi -> store slot = l31*2+hi
                const int kc = nt * 2 + (q >> 1);
                u32x4 ck;
                if (hi == 0) ck = (u32x4){p0, p1, r0, r1};   // own j=0..3
                else         ck = (u32x4){r0, r1, p0, p1};   // own j=4..7
                *(u32x4*)&out[base + (size_t)kc * 512 + (size_t)slot * 8] = ck;
            }
        }
    }
}

// ---------------- max-sim v4 (UNCHANGED): 32x32x16 MFMA, coalesced frags -----
__global__ __launch_bounds__(256) void maxsim_kernel(
    const u16* __restrict__ qbf, const u16* __restrict__ dbf,
    float* __restrict__ logits)
{
    __shared__ float smax[4][8][2][32];   // [wave][dbi][qs][qcol]
    const int tid  = threadIdx.x;
    const int wid  = tid >> 6;
    const int lane = tid & 63;
    const int l31  = lane & 31;
    const int soff = ((lane & 31) * 2 + (lane >> 5)) * 8;

    const int qb0 = (blockIdx.x >> 4) * 2;
    const int db0 = (blockIdx.x & 15) * 8;

    short8 bq[2][8];
    #pragma unroll
    for (int qs = 0; qs < 2; ++qs) {
        const u16* qb_base = qbf + (size_t)(qb0 + qs) * 4096 + soff;
        #pragma unroll
        for (int kc = 0; kc < 8; ++kc)
            bq[qs][kc] = *(const short8*)(qb_base + kc * 512);
    }

    #pragma unroll 2
    for (int dbi = 0; dbi < 8; ++dbi) {
        const u16* dt = dbf + (size_t)((db0 + dbi) * 4 + wid) * 4096 + soff;
        short8 af[8];
        #pragma unroll
        for (int kc = 0; kc < 8; ++kc)
            af[kc] = *(const short8*)(dt + kc * 512);

        f32x16 acc0 = {0.f}, acc1 = {0.f};
        #pragma unroll
        for (int kc = 0; kc < 8; ++kc) {
            acc0 = __builtin_amdgcn_mfma_f32_32x32x16_bf16(af[kc], bq[0][kc], acc0, 0, 0, 0);
            acc1 = __builtin_amdgcn_mfma_f32_32x32x16_bf16(af[kc], bq[1][kc], acc1, 0, 0, 0);
        }

        #pragma unroll
        for (int qs = 0; qs < 2; ++qs) {
            const f32x16 a = qs ? acc1 : acc0;
            float m0 = fmaxf(a[0], a[1]),   m1 = fmaxf(a[2], a[3]);
            float m2 = fmaxf(a[4], a[5]),   m3 = fmaxf(a[6], a[7]);
            float m4 = fmaxf(a[8], a[9]),   m5 = fmaxf(a[10], a[11]);
            float m6 = fmaxf(a[12], a[13]), m7 = fmaxf(a[14], a[15]);
            float m = fmaxf(fmaxf(fmaxf(m0, m1), fmaxf(m2, m3)),
                            fmaxf(fmaxf(m4, m5), fmaxf(m6, m7)));
            m = fmaxf(m, __shfl_xor(m, 32));
            if (lane < 32) smax[wid][dbi][qs][l31] = m;
        }
    }
    __syncthreads();

    {
        const int dbi = tid >> 5;
        const int col = tid & 31;
        float v0 = fmaxf(fmaxf(smax[0][dbi][0][col], smax[1][dbi][0][col]),
                         fmaxf(smax[2][dbi][0][col], smax[3][dbi][0][col]));
        float v1 = fmaxf(fmaxf(smax[0][dbi][1][col], smax[1][dbi][1][col]),
                         fmaxf(smax[2][dbi][1][col], smax[3][dbi][1][col]));
        v0 += __shfl_xor(v0, 1);  v1 += __shfl_xor(v1, 1);
        v0 += __shfl_xor(v0, 2);  v1 += __shfl_xor(v1, 2);
        v0 += __shfl_xor(v0, 4);  v1 += __shfl_xor(v1, 4);
        v0 += __shfl_xor(v0, 8);  v1 += __shfl_xor(v1, 8);
        v0 += __shfl_xor(v0, 16); v1 += __shfl_xor(v1, 16);
        if (col == 0) {
            logits[(size_t)qb0 * 128 + db0 + dbi]       = v0;
            logits[(size_t)(qb0 + 1) * 128 + db0 + dbi] = v1;
        }
    }
}

extern "C" void kernel_launch(void* const* d_in, const int* in_sizes, int n_in,
                              void* d_out, int out_size, void* d_ws, size_t ws_size,
                              hipStream_t stream)
{
    const float* query_h = (const float*)d_in[0];  // [128,32,256]
    const float* doc_h   = (const float*)d_in[1];  // [128,128,256]
    const float* W       = (const float*)d_in[2];  // [256,128]
    const float* bias    = (const float*)d_in[3];  // [128]
    float* logits = (float*)d_out;                 // [128,128]

    u16* qbf = (u16*)d_ws;                         // 128 tiles x 4096 (1 MB)
    u16* dbf = qbf + (size_t)128 * 4096;           // 512 tiles x 4096 (4 MB)
    u16* whi = dbf + (size_t)512 * 4096;           // 4096 chunks x 8 (64 KB)
    u16* wlo = whi + (size_t)4096 * 8;             // 64 KB

    prep_w   <<<dim3(16),   dim3(256), 0, stream>>>(W, whi, wlo);
    proj_mfma<<<dim3(160),  dim3(256), 0, stream>>>(query_h, doc_h, bias, whi, wlo, qbf, dbf);
    maxsim_kernel<<<dim3(1024), dim3(256), 0, stream>>>(qbf, dbf, logits);
}

// Round 7
// 104.280 us; speedup vs baseline: 1.3996x; 1.0119x over previous
//
#include <hip/hip_runtime.h>

typedef unsigned short u16;
typedef unsigned int u32;
typedef __attribute__((ext_vector_type(8))) short short8;
typedef __attribute__((ext_vector_type(16))) float f32x16;
typedef __attribute__((ext_vector_type(4))) float f32x4;
typedef __attribute__((ext_vector_type(4))) unsigned int u32x4;

#define H 256
#define D 128

// Fragment-chunk layout for normalized bf16 embeddings (consumed by maxsim):
//   elem index = tile*4096 + kc*512 + (l31*2 + lg2)*8 + j
//   holds Y[token = tile*32 + l31][k = kc*16 + lg2*8 + j]
// A wave's 64 lanes (slot = l31*2+lg2) load/store 1024 CONTIGUOUS bytes per kc.

union V16 { u32x4 u; short8 s; f32x4 f; };

static __device__ inline u32 bf16pk_rne(float a, float b) {
    u32 ua = __float_as_uint(a), ub = __float_as_uint(b);
    ua = ua + 0x7FFFu + ((ua >> 16) & 1u);
    ub = ub + 0x7FFFu + ((ub >> 16) & 1u);
    return (ua >> 16) | (ub & 0xFFFF0000u);
}

// ---------------- prep_w: W (fp32 [H][D]) -> bf16 hi/lo A-fragments ----------
__global__ __launch_bounds__(256) void prep_w(
    const float* __restrict__ W, u16* __restrict__ whi, u16* __restrict__ wlo)
{
    const int g   = blockIdx.x * 256 + threadIdx.x;   // 0..4095
    const int slot = g & 63;
    const int kc  = (g >> 6) & 15;
    const int nt  = g >> 10;
    const int l31 = slot >> 1;
    const int lg2 = slot & 1;
    const int k0  = kc * 16 + lg2 * 8;
    const int n   = nt * 32 + l31;

    u32 hw[4], lw[4];
    #pragma unroll
    for (int p = 0; p < 4; ++p) {
        float a = W[(size_t)(k0 + 2*p)     * D + n];
        float b = W[(size_t)(k0 + 2*p + 1) * D + n];
        u32 ua = __float_as_uint(a), ub = __float_as_uint(b);
        u32 ha = ua & 0xFFFF0000u,   hb = ub & 0xFFFF0000u;
        hw[p] = (ua >> 16) | hb;                       // hi = truncation
        float la = a - __uint_as_float(ha);
        float lb = b - __uint_as_float(hb);
        u32 ra = __float_as_uint(la); ra += 0x7FFFu + ((ra >> 16) & 1u);
        u32 rb = __float_as_uint(lb); rb += 0x7FFFu + ((rb >> 16) & 1u);
        lw[p] = (ra >> 16) | (rb & 0xFFFF0000u);       // lo = RNE bf16
    }
    u32x4 hv = {hw[0], hw[1], hw[2], hw[3]};
    u32x4 lv = {lw[0], lw[1], lw[2], lw[3]};
    *(u32x4*)&whi[(size_t)g * 8] = hv;
    *(u32x4*)&wlo[(size_t)g * 8] = lv;
}

// ---------------- proj v3: LDS-staged X + 3-term bf16-split MFMA -------------
// grid: 32 (query) + 128 (doc) blocks x 256 thr. Wave handles 32 tokens.
// X staged wave-private in LDS (swizzled 16B slots) so global reads are
// coalesced (1 KB/instr) instead of 32 lines/instr.
__global__ __launch_bounds__(256) void proj_mfma(
    const float* __restrict__ Xq, const float* __restrict__ Xd,
    const float* __restrict__ bias,
    const u16* __restrict__ whi, const u16* __restrict__ wlo,
    u16* __restrict__ outq, u16* __restrict__ outd)
{
    __shared__ float xst[4][32][256];   // 128 KB; slot s of row t holds slot s^(t&7)
    const int tid  = threadIdx.x;
    const int wid  = tid >> 6;
    const int lane = tid & 63;
    const int l31  = lane & 31;
    const int hi   = lane >> 5;
    const int slot = l31 * 2 + hi;

    const float* X; u16* out; int trow0;
    if (blockIdx.x < 32) { X = Xq; out = outq; trow0 = blockIdx.x * 128 + wid * 32; }
    else { X = Xd; out = outd; trow0 = (blockIdx.x - 32) * 128 + wid * 32; }

    // ---- stage: 32 rows x 1 KB, coalesced; wave-private (no barrier) ----
    {
        float* xw = &xst[wid][0][0];
        const float* xs0 = X + (size_t)trow0 * H;
        #pragma unroll
        for (int t = 0; t < 32; ++t) {
            f32x4 v = *(const f32x4*)&xs0[(size_t)t * H + lane * 4];
            int sl = lane ^ (t & 7);
            *(f32x4*)&xw[t * 256 + sl * 4] = v;
        }
    }

    f32x16 acc[4];
    #pragma unroll
    for (int nt = 0; nt < 4; ++nt) acc[nt] = (f32x16){0.f};

    const float* xw = &xst[wid][0][0];
    #pragma unroll
    for (int kc = 0; kc < 16; ++kc) {
        // this lane's B-frag source: row l31, fp32 slots g, g+1 (swizzled)
        const int g = kc * 4 + hi * 2;
        const int sw = l31 & 7;
        f32x4 va = *(const f32x4*)&xw[l31 * 256 + ((g ^ sw) << 2)];
        f32x4 vb = *(const f32x4*)&xw[l31 * 256 + (((g + 1) ^ sw) << 2)];
        float e[8];
        #pragma unroll
        for (int i = 0; i < 4; ++i) { e[i] = va[i]; e[i + 4] = vb[i]; }

        V16 xh, xl;
        u32 xhu[4], xlu[4];
        #pragma unroll
        for (int p = 0; p < 4; ++p) {
            u32 u0 = __float_as_uint(e[2*p]), u1 = __float_as_uint(e[2*p+1]);
            u32 h0 = u0 & 0xFFFF0000u,        h1 = u1 & 0xFFFF0000u;
            xhu[p] = (u0 >> 16) | h1;                          // hi = trunc
            float l0 = e[2*p]   - __uint_as_float(h0);         // exact residual
            float l1 = e[2*p+1] - __uint_as_float(h1);
            xlu[p] = (__float_as_uint(l0) >> 16) |
                     (__float_as_uint(l1) & 0xFFFF0000u);
        }
        xh.u = (u32x4){xhu[0], xhu[1], xhu[2], xhu[3]};
        xl.u = (u32x4){xlu[0], xlu[1], xlu[2], xlu[3]};

        #pragma unroll
        for (int nt = 0; nt < 4; ++nt) {
            V16 wh, wl;
            const size_t fo = (size_t)((nt * 16 + kc) * 64 + slot) * 8;
            wh.u = *(const u32x4*)&whi[fo];
            wl.u = *(const u32x4*)&wlo[fo];
            acc[nt] = __builtin_amdgcn_mfma_f32_32x32x16_bf16(wh.s, xh.s, acc[nt], 0, 0, 0);
            acc[nt] = __builtin_amdgcn_mfma_f32_32x32x16_bf16(wl.s, xh.s, acc[nt], 0, 0, 0);
            acc[nt] = __builtin_amdgcn_mfma_f32_32x32x16_bf16(wh.s, xl.s, acc[nt], 0, 0, 0);
        }
    }

    // bias + sum-sq (lane holds 64 of token l31's 128 outputs; partner has rest)
    float ss = 0.f;
    #pragma unroll
    for (int nt = 0; nt < 4; ++nt) {
        #pragma unroll
        for (int q = 0; q < 4; ++q) {
            f32x4 b4 = *(const f32x4*)&bias[nt * 32 + q * 8 + hi * 4];
            #pragma unroll
            for (int i = 0; i < 4; ++i) {
                float v = acc[nt][q*4+i] + b4[i];
                acc[nt][q*4+i] = v;
                ss += v * v;
            }
        }
    }
    ss += __shfl_xor(ss, 32);
    const float inv = 1.0f / fmaxf(sqrtf(ss), 1e-12f);

    // pack bf16, pair-exchange (l <-> l+32), coalesced frag-layout stores
    const size_t base = (size_t)(trow0 >> 5) * 4096;
    #pragma unroll
    for (int nt = 0; nt < 4; ++nt) {
        #pragma unroll
        for (int q = 0; q < 4; ++q) {
            float v0 = acc[nt][q*4+0] * inv, v1 = acc[nt][q*4+1] * inv;
            float v2 = acc[nt][q*4+2] * inv, v3 = acc[nt][q*4+3] * inv;
            u32 p0 = bf16pk_rne(v0, v1), p1 = bf16pk_rne(v2, v3);
            u32 r0 = __shfl_xor(p0, 32), r1 = __shfl_xor(p1, 32);
            if ((q & 1) == hi) {
                const int kc = nt * 2 + (q >> 1);
                u32x4 ck;
                if (hi == 0) ck = (u32x4){p0, p1, r0, r1};
                else         ck = (u32x4){r0, r1, p0, p1};
                *(u32x4*)&out[base + (size_t)kc * 512 + (size_t)slot * 8] = ck;
            }
        }
    }
}

// ---------------- max-sim v5: coalesced frags + af register double-buffer ----
// block: 256 threads (4 waves). Tile: 2 qb x 8 db. grid = 64*16 = 1024.
// Loads for db i+1 issue BEFORE the MFMA+reduce of db i (L2 latency hidden;
// loads are coalesced now, so latency — not TA throughput — is the exposure).

#define LOAD_AF(AF, DBI)                                                       \
    {                                                                          \
        const u16* dt_ = dbf + (size_t)((db0 + (DBI)) * 4 + wid) * 4096 + soff;\
        _Pragma("unroll")                                                      \
        for (int kc = 0; kc < 8; ++kc)                                         \
            AF[kc] = *(const short8*)(dt_ + kc * 512);                         \
    }

#define COMPUTE_AF(AF, DBI)                                                    \
    {                                                                          \
        f32x16 acc0 = {0.f}, acc1 = {0.f};                                     \
        _Pragma("unroll")                                                      \
        for (int kc = 0; kc < 8; ++kc) {                                       \
            acc0 = __builtin_amdgcn_mfma_f32_32x32x16_bf16(AF[kc], bq[0][kc],  \
                                                           acc0, 0, 0, 0);     \
            acc1 = __builtin_amdgcn_mfma_f32_32x32x16_bf16(AF[kc], bq[1][kc],  \
                                                           acc1, 0, 0, 0);     \
        }                                                                      \
        _Pragma("unroll")                                                      \
        for (int qs = 0; qs < 2; ++qs) {                                       \
            const f32x16 a = qs ? acc1 : acc0;                                 \
            float m0 = fmaxf(a[0], a[1]),   m1 = fmaxf(a[2], a[3]);            \
            float m2 = fmaxf(a[4], a[5]),   m3 = fmaxf(a[6], a[7]);            \
            float m4 = fmaxf(a[8], a[9]),   m5 = fmaxf(a[10], a[11]);          \
            float m6 = fmaxf(a[12], a[13]), m7 = fmaxf(a[14], a[15]);          \
            float m = fmaxf(fmaxf(fmaxf(m0, m1), fmaxf(m2, m3)),               \
                            fmaxf(fmaxf(m4, m5), fmaxf(m6, m7)));              \
            m = fmaxf(m, __shfl_xor(m, 32));                                   \
            if (lane < 32) smax[wid][DBI][qs][l31] = m;                        \
        }                                                                      \
    }

__global__ __launch_bounds__(256) void maxsim_kernel(
    const u16* __restrict__ qbf, const u16* __restrict__ dbf,
    float* __restrict__ logits)
{
    __shared__ float smax[4][8][2][32];   // [wave][dbi][qs][qcol]
    const int tid  = threadIdx.x;
    const int wid  = tid >> 6;
    const int lane = tid & 63;
    const int l31  = lane & 31;
    const int soff = ((lane & 31) * 2 + (lane >> 5)) * 8;

    const int qb0 = (blockIdx.x >> 4) * 2;
    const int db0 = (blockIdx.x & 15) * 8;

    short8 bq[2][8];
    #pragma unroll
    for (int qs = 0; qs < 2; ++qs) {
        const u16* qb_base = qbf + (size_t)(qb0 + qs) * 4096 + soff;
        #pragma unroll
        for (int kc = 0; kc < 8; ++kc)
            bq[qs][kc] = *(const short8*)(qb_base + kc * 512);
    }

    short8 afA[8], afB[8];
    LOAD_AF(afA, 0);
    #pragma unroll
    for (int dbi = 0; dbi < 8; dbi += 2) {
        LOAD_AF(afB, dbi + 1);
        COMPUTE_AF(afA, dbi);
        if (dbi + 2 < 8) LOAD_AF(afA, dbi + 2);
        COMPUTE_AF(afB, dbi + 1);
    }
    __syncthreads();

    {
        const int dbi = tid >> 5;
        const int col = tid & 31;
        float v0 = fmaxf(fmaxf(smax[0][dbi][0][col], smax[1][dbi][0][col]),
                         fmaxf(smax[2][dbi][0][col], smax[3][dbi][0][col]));
        float v1 = fmaxf(fmaxf(smax[0][dbi][1][col], smax[1][dbi][1][col]),
                         fmaxf(smax[2][dbi][1][col], smax[3][dbi][1][col]));
        v0 += __shfl_xor(v0, 1);  v1 += __shfl_xor(v1, 1);
        v0 += __shfl_xor(v0, 2);  v1 += __shfl_xor(v1, 2);
        v0 += __shfl_xor(v0, 4);  v1 += __shfl_xor(v1, 4);
        v0 += __shfl_xor(v0, 8);  v1 += __shfl_xor(v1, 8);
        v0 += __shfl_xor(v0, 16); v1 += __shfl_xor(v1, 16);
        if (col == 0) {
            logits[(size_t)qb0 * 128 + db0 + dbi]       = v0;
            logits[(size_t)(qb0 + 1) * 128 + db0 + dbi] = v1;
        }
    }
}

extern "C" void kernel_launch(void* const* d_in, const int* in_sizes, int n_in,
                              void* d_out, int out_size, void* d_ws, size_t ws_size,
                              hipStream_t stream)
{
    const float* query_h = (const float*)d_in[0];  // [128,32,256]
    const float* doc_h   = (const float*)d_in[1];  // [128,128,256]
    const float* W       = (const float*)d_in[2];  // [256,128]
    const float* bias    = (const float*)d_in[3];  // [128]
    float* logits = (float*)d_out;                 // [128,128]

    u16* qbf = (u16*)d_ws;                         // 128 tiles x 4096 (1 MB)
    u16* dbf = qbf + (size_t)128 * 4096;           // 512 tiles x 4096 (4 MB)
    u16* whi = dbf + (size_t)512 * 4096;           // 64 KB
    u16* wlo = whi + (size_t)4096 * 8;             // 64 KB

    prep_w   <<<dim3(16),   dim3(256), 0, stream>>>(W, whi, wlo);
    proj_mfma<<<dim3(160),  dim3(256), 0, stream>>>(query_h, doc_h, bias, whi, wlo, qbf, dbf);
    maxsim_kernel<<<dim3(1024), dim3(256), 0, stream>>>(qbf, dbf, logits);
}